// Round 10
// baseline (192.014 us; speedup 1.0000x reference)
//
#include <hip/hip_runtime.h>
#include <math.h>

// Problem constants (fixed by reference)
#define B_ 2
#define H_ 16
#define L_ 4096
#define D_ 128
#define F_ 64
#define F2_ 128
#define S_ 64
#define N_ 64
#define BH_ 32
#define NBT_ 2048
#define EPS_ 1e-6f
#define SCALING_ 0.08838834764831845f  // 128^-0.5

typedef float f32x4 __attribute__((ext_vector_type(4)));
typedef short s16x8 __attribute__((ext_vector_type(8)));
typedef short s16x4 __attribute__((ext_vector_type(4)));

#define MFMA(a, b, c) __builtin_amdgcn_mfma_f32_16x16x32_bf16(a, b, c, 0, 0, 0)

// packed f32x2 -> bf16x2 (RNE) in ONE instruction (gfx950)
__device__ __forceinline__ unsigned cvt_pk_bf16(float lo, float hi) {
  unsigned r;
  asm("v_cvt_pk_bf16_f32 %0, %1, %2" : "=v"(r) : "v"(lo), "v"(hi));
  return r;
}

__device__ __forceinline__ short f2bf(float f) {
  unsigned u = __float_as_uint(f);
  u += 0x7fffu + ((u >> 16) & 1u);   // RNE (cold paths only)
  return (short)(u >> 16);
}
__device__ __forceinline__ float bf2f(short s) {
  return __uint_as_float(((unsigned)(unsigned short)s) << 16);
}

// 8 consecutive fp32 -> bf16 fragment (4 cvt_pk instructions)
__device__ __forceinline__ s16x8 frag_f32(const float* p) {
  f32x4 a = *(const f32x4*)p;
  f32x4 b = *(const f32x4*)(p + 4);
  union { unsigned u[4]; s16x8 s; } r;
  r.u[0] = cvt_pk_bf16(a[0], a[1]);
  r.u[1] = cvt_pk_bf16(a[2], a[3]);
  r.u[2] = cvt_pk_bf16(b[0], b[1]);
  r.u[3] = cvt_pk_bf16(b[2], b[3]);
  return r.s;
}

// XOR swizzle: byte ^= (row&7)<<4 within a row. Used for LDS bank-conflict
// avoidance AND baked into the St/VT global layouts.
__device__ __forceinline__ s16x8 swz_frag(const short* base, int row, int rowBytes, int colByte) {
  int byte = row * rowBytes + (colByte ^ ((row & 7) << 4));
  return *(const s16x8*)((const char*)base + byte);
}
__device__ __forceinline__ void lds_w16(short* lds, int row, int rowBytes, int colByte, short v) {
  int byte = row * rowBytes + (colByte ^ ((row & 7) << 4));
  *(short*)((char*)lds + byte) = v;
}

// ---------------------------------------------------------------------------
// prep_w: Wt[h][f][d] bf16 (transposed) so B-fragments of u=x@W are contiguous.
// ---------------------------------------------------------------------------
__global__ __launch_bounds__(256)
void prep_w(const float* __restrict__ W, short* __restrict__ Wt)
{
  const int h = blockIdx.x;
  const int tid = threadIdx.x;
  const int f = tid & 63, gq = tid >> 6;
  const float* Wh = W + (size_t)h * D_ * F_;
  short* Wo = Wt + (size_t)h * F_ * D_ + (size_t)f * D_ + gq * 32;
  short buf[32];
#pragma unroll
  for (int j = 0; j < 32; ++j) buf[j] = f2bf(Wh[(size_t)(gq * 32 + j) * F_ + f]);
#pragma unroll
  for (int j2 = 0; j2 < 4; ++j2) {
    s16x8 v;
#pragma unroll
    for (int e = 0; e < 8; ++e) v[e] = buf[j2 * 8 + e];
    *(s16x8*)(Wo + j2 * 8) = v;
  }
}

// ---------------------------------------------------------------------------
// phase1: stage V -> VTs LDS image (transpose + bf16, baked swizzle);
// u = k@W (MFMA); phi_k -> phiT (LDS); dZ colsums (bf16); dSt (MFMA);
// coalesced VT + St global writes. All bf16 packing via v_cvt_pk_bf16_f32.
// ---------------------------------------------------------------------------
__global__ __launch_bounds__(256, 3)
void bslh_phase1(const float* __restrict__ K, const float* __restrict__ V,
                 const short* __restrict__ Wt, short* __restrict__ VT,
                 short* __restrict__ dSt, short* __restrict__ dZ)
{
  __shared__ __align__(16) char lds[32 * 1024];
  short* phiT = (short*)lds;              // 16KB [128 f][128B] swizzled
  short* VTs = (short*)(lds + 16384);     // 16KB [128 d][128B] baked layout

  const int blk = blockIdx.x;
  const int bh = blk / N_;
  const int h = bh % H_;
  const int tid = threadIdx.x;
  const int wave = tid >> 6, lane = tid & 63;
  const int rl = lane & 15, g = lane >> 4, kl = g * 8;
  const int r0 = wave * 16;

  // ---- stage V -> VTs (transpose + bf16) ----
  {
    const float4* gv = (const float4*)(V + (size_t)blk * S_ * D_);
#pragma unroll
    for (int ii = 0; ii < 8; ++ii) {
      int idx = tid + 256 * ii;
      int s = idx >> 5, c = (idx & 31) * 4;
      float4 v = gv[idx];
      float o0 = __shfl_xor(v.x, 32, 64);
      float o1 = __shfl_xor(v.y, 32, 64);
      float o2 = __shfl_xor(v.z, 32, 64);
      float o3 = __shfl_xor(v.w, 32, 64);
      if (!(tid & 32)) {
        float m[4] = {v.x, v.y, v.z, v.w};
        float o[4] = {o0, o1, o2, o3};
#pragma unroll
        for (int j = 0; j < 4; ++j) {
          int d = c + j;
          unsigned pk = cvt_pk_bf16(m[j], o[j]);
          int byte = d * 128 + ((s * 2) ^ ((d & 7) << 4));
          *(unsigned*)((char*)VTs + byte) = pk;
        }
      }
    }
  }

  const float* Kb = K + (size_t)blk * (S_ * D_);
  const short* Wh = Wt + (size_t)h * (F_ * D_);
  const f32x4 z4 = {0.f, 0.f, 0.f, 0.f};

  // ---- u = k @ W ----
  f32x4 uacc[4] = {z4, z4, z4, z4};
#pragma unroll
  for (int ks = 0; ks < 4; ++ks) {
    s16x8 a = frag_f32(Kb + (size_t)(r0 + rl) * D_ + ks * 32 + kl);
#pragma unroll
    for (int tn = 0; tn < 4; ++tn) {
      s16x8 b = *(const s16x8*)(Wh + (size_t)(tn * 16 + rl) * D_ + ks * 32 + kl);
      uacc[tn] = MFMA(a, b, uacc[tn]);
    }
  }

  // ---- phi = [softmax(u), softmax(-u)] -> phiT (transposed, swizzled) ----
#pragma unroll
  for (int reg = 0; reg < 4; ++reg) {
    float mx = -1e30f, mn = 1e30f;
#pragma unroll
    for (int tn = 0; tn < 4; ++tn) {
      mx = fmaxf(mx, uacc[tn][reg]);
      mn = fminf(mn, uacc[tn][reg]);
    }
#pragma unroll
    for (int o = 1; o <= 8; o <<= 1) {
      mx = fmaxf(mx, __shfl_xor(mx, o, 64));
      mn = fminf(mn, __shfl_xor(mn, o, 64));
    }
    float ep[4], em[4], sp = 0.f, sm = 0.f;
#pragma unroll
    for (int tn = 0; tn < 4; ++tn) {
      ep[tn] = __expf(uacc[tn][reg] - mx); sp += ep[tn];
      em[tn] = __expf(mn - uacc[tn][reg]); sm += em[tn];
    }
#pragma unroll
    for (int o = 1; o <= 8; o <<= 1) {
      sp += __shfl_xor(sp, o, 64);
      sm += __shfl_xor(sm, o, 64);
    }
    const float rp = 1.f / sp, rm = 1.f / sm;
    const int srow = r0 + g * 4 + reg;
#pragma unroll
    for (int tn = 0; tn < 4; ++tn) {
      int f = tn * 16 + rl;
      unsigned pk = cvt_pk_bf16(ep[tn] * rp, em[tn] * rm);
      lds_w16(phiT, f,      2 * S_, srow * 2, (short)pk);
      lds_w16(phiT, f + 64, 2 * S_, srow * 2, (short)(pk >> 16));
    }
  }
  __syncthreads();   // phiT + VTs images complete (cross-wave consumers below)

  // ---- write VT global (coalesced float4 copy of the 16KB image) ----
  {
    float4* dst = (float4*)(VT + (size_t)blk * (D_ * S_));
    const float4* src = (const float4*)VTs;
#pragma unroll
    for (int i = 0; i < 4; ++i) dst[tid + 256 * i] = src[tid + 256 * i];
  }

  // ---- dZ[f] = sum_s phi[s][f] (bf16 store) ----
  {
    const int f = tid >> 1, half = tid & 1;
    float z = 0.f;
#pragma unroll
    for (int j2 = 0; j2 < 4; ++j2) {
      s16x8 v = swz_frag(phiT, f, 2 * S_, (half * 32 + j2 * 8) * 2);
#pragma unroll
      for (int e = 0; e < 8; ++e) z += bf2f(v[e]);
    }
    z += __shfl_xor(z, 1, 64);
    if (half == 0) dZ[(size_t)blk * F2_ + f] = f2bf(z);
  }

  // ---- dSt[d][f] = sum_s v[s][d]*phi[s][f]; wave owns d-rows 32w..32w+31 ----
  f32x4 acc[2][8];
#pragma unroll
  for (int tm = 0; tm < 2; ++tm)
#pragma unroll
    for (int tn = 0; tn < 8; ++tn) acc[tm][tn] = z4;

#pragma unroll
  for (int ks = 0; ks < 2; ++ks) {
    s16x8 a[2];
#pragma unroll
    for (int tm = 0; tm < 2; ++tm)
      a[tm] = swz_frag(VTs, wave * 32 + tm * 16 + rl, 2 * S_, (ks * 32 + kl) * 2);
#pragma unroll
    for (int tn = 0; tn < 8; ++tn) {
      s16x8 b = swz_frag(phiT, tn * 16 + rl, 2 * S_, (ks * 32 + kl) * 2);
#pragma unroll
      for (int tm = 0; tm < 2; ++tm)
        acc[tm][tn] = MFMA(a[tm], b, acc[tm][tn]);
    }
  }
  __syncthreads();   // all phiT/VTs reads done; reuse lds as St image

  // ---- pack acc into LDS St image (baked swizzle), coalesced store ----
  short* Stb = (short*)lds;
#pragma unroll
  for (int tm = 0; tm < 2; ++tm)
#pragma unroll
    for (int tn = 0; tn < 8; ++tn)
#pragma unroll
      for (int reg = 0; reg < 4; ++reg) {
        float v0 = acc[tm][tn][reg];
        float v1 = __shfl_xor(v0, 1, 64);
        if (!(lane & 1)) {
          int drow = wave * 32 + tm * 16 + g * 4 + reg;
          int fcol = tn * 16 + rl;
          unsigned pk = cvt_pk_bf16(v0, v1);
          int byte = drow * 256 + ((fcol * 2) ^ ((drow & 7) << 4));
          *(unsigned*)((char*)Stb + byte) = pk;
        }
      }
  __syncthreads();

  float4* dst = (float4*)(dSt + (size_t)blk * (F2_ * D_));
  const float4* srcl = (const float4*)lds;
#pragma unroll
  for (int i = 0; i < 8; ++i) dst[tid + 256 * i] = srcl[tid + 256 * i];
}

// ---------------------------------------------------------------------------
// scan: blocks [0,512) -> exclusive prefix of St in 4-short chunks;
// blocks [512,516) -> exclusive prefix of dZ (bf16).
// ---------------------------------------------------------------------------
__global__ __launch_bounds__(256)
void bslh_scan(short* __restrict__ St, short* __restrict__ dZ)
{
  const int tid = threadIdx.x;
  if (blockIdx.x < 512) {
    const int idx = blockIdx.x * 256 + tid;      // 131072 threads
    const int bh = idx >> 12;
    const int rem = idx & 4095;
    short* p = St + (size_t)bh * N_ * (F2_ * D_) + (size_t)rem * 4;
    float run[4] = {0.f, 0.f, 0.f, 0.f};
#pragma unroll 4
    for (int n = 0; n < N_; ++n) {
      s16x4 v = *(const s16x4*)p;
      union { unsigned u[2]; s16x4 s; } o;
      o.u[0] = cvt_pk_bf16(run[0], run[1]);
      o.u[1] = cvt_pk_bf16(run[2], run[3]);
#pragma unroll
      for (int e = 0; e < 4; ++e) run[e] += bf2f(v[e]);
      *(s16x4*)p = o.s;
      p += F2_ * D_;
    }
  } else {
    const int idx = (blockIdx.x - 512) * 256 + tid;  // 1024 threads
    const int bh = idx >> 5, e = idx & 31;
    short* p = dZ + (size_t)bh * N_ * F2_ + (size_t)e * 4;
    float run[4] = {0.f, 0.f, 0.f, 0.f};
#pragma unroll 4
    for (int n = 0; n < N_; ++n) {
      s16x4 v = *(const s16x4*)p;
      union { unsigned u[2]; s16x4 s; } o;
      o.u[0] = cvt_pk_bf16(run[0], run[1]);
      o.u[1] = cvt_pk_bf16(run[2], run[3]);
#pragma unroll
      for (int e2 = 0; e2 < 4; ++e2) run[e2] += bf2f(v[e2]);
      *(s16x4*)p = o.s;
      p += F2_;
    }
  }
}

// ---------------------------------------------------------------------------
// phase3 — barrier-free, fully unrolled, cvt_pk everywhere: phi and Pl are
// wave-private 16-row LDS bands; cl in registers; Q and K converted from
// fp32 via packed cvt (R7-measured faster than the Kbf round-trip).
// ---------------------------------------------------------------------------
__global__ __launch_bounds__(256, 4)
void bslh_phase3(const float* __restrict__ Q, const float* __restrict__ K,
                 const short* __restrict__ VT, const short* __restrict__ Wt,
                 const short* __restrict__ St, const short* __restrict__ Zp,
                 const float* __restrict__ alphap, float* __restrict__ Out)
{
  __shared__ __align__(16) short phi[S_ * F2_];  // 16KB; rows r0..r0+15 per wave
  __shared__ __align__(16) short Pl[S_ * S_];    // 8KB;  rows r0..r0+15 per wave

  const int blk = blockIdx.x;
  const int bh = blk / N_;
  const int h = bh % H_;
  const int tid = threadIdx.x;
  const int wave = tid >> 6, lane = tid & 63;
  const int rl = lane & 15, g = lane >> 4, kl = g * 8;
  const int r0 = wave * 16;

  const float* Qb = Q + (size_t)blk * (S_ * D_);
  const float* Kb = K + (size_t)blk * (S_ * D_);
  const short* Sb = St + (size_t)blk * (F2_ * D_);
  const short* VTb = VT + (size_t)blk * (D_ * S_);
  const short* Wh = Wt + (size_t)h * (F_ * D_);
  const short* Zb = Zp + (size_t)blk * F2_;
  const float w = 1.f / (1.f + __expf(-alphap[0]));
  const f32x4 z4 = {0.f, 0.f, 0.f, 0.f};

  // Z prefix values this thread needs (per tn: f and f+64)
  float zf0[4], zf1[4];
#pragma unroll
  for (int tn = 0; tn < 4; ++tn) {
    zf0[tn] = bf2f(Zb[tn * 16 + rl]);
    zf1[tn] = bf2f(Zb[64 + tn * 16 + rl]);
  }

  // ---- u = q @ W (keep Q A-fragments) ----
  s16x8 aq[4];
  f32x4 uacc[4] = {z4, z4, z4, z4};
#pragma unroll
  for (int ks = 0; ks < 4; ++ks) {
    aq[ks] = frag_f32(Qb + (size_t)(r0 + rl) * D_ + ks * 32 + kl);
#pragma unroll
    for (int tn = 0; tn < 4; ++tn) {
      s16x8 b = *(const s16x8*)(Wh + (size_t)(tn * 16 + rl) * D_ + ks * 32 + kl);
      uacc[tn] = MFMA(aq[ks], b, uacc[tn]);
    }
  }

  // ---- scores = q @ k^T (K converted from fp32 inline) ----
  f32x4 sacc[4] = {z4, z4, z4, z4};
#pragma unroll
  for (int ks = 0; ks < 4; ++ks) {
#pragma unroll
    for (int tn = 0; tn < 4; ++tn) {
      s16x8 b = frag_f32(Kb + (size_t)(tn * 16 + rl) * D_ + ks * 32 + kl);
      sacc[tn] = MFMA(aq[ks], b, sacc[tn]);
    }
  }

  // ---- phi_q softmaxes + in-register cl ----
  float cl[4];
#pragma unroll
  for (int reg = 0; reg < 4; ++reg) {
    float mx = -1e30f, mn = 1e30f;
#pragma unroll
    for (int tn = 0; tn < 4; ++tn) {
      mx = fmaxf(mx, uacc[tn][reg]);
      mn = fminf(mn, uacc[tn][reg]);
    }
#pragma unroll
    for (int o = 1; o <= 8; o <<= 1) {
      mx = fmaxf(mx, __shfl_xor(mx, o, 64));
      mn = fminf(mn, __shfl_xor(mn, o, 64));
    }
    float ep[4], em[4], sp = 0.f, sm = 0.f;
#pragma unroll
    for (int tn = 0; tn < 4; ++tn) {
      ep[tn] = __expf(uacc[tn][reg] - mx); sp += ep[tn];
      em[tn] = __expf(mn - uacc[tn][reg]); sm += em[tn];
    }
#pragma unroll
    for (int o = 1; o <= 8; o <<= 1) {
      sp += __shfl_xor(sp, o, 64);
      sm += __shfl_xor(sm, o, 64);
    }
    const float rp = 1.f / sp, rm = 1.f / sm;
    const int srow = r0 + g * 4 + reg;
    float dp = 0.f;
#pragma unroll
    for (int tn = 0; tn < 4; ++tn) {
      float pv = ep[tn] * rp, mv = em[tn] * rm;
      dp = fmaf(pv, zf0[tn], dp);
      dp = fmaf(mv, zf1[tn], dp);
      int f = tn * 16 + rl;
      unsigned pk = cvt_pk_bf16(pv, mv);
      lds_w16(phi, srow, 2 * F2_, f * 2,        (short)pk);
      lds_w16(phi, srow, 2 * F2_, (f + 64) * 2, (short)(pk >> 16));
    }
#pragma unroll
    for (int o = 1; o <= 8; o <<= 1) dp += __shfl_xor(dp, o, 64);
    cl[reg] = (1.f - w) / fmaxf(dp, EPS_);
  }

  // ---- scores softmax -> Pl (wave-private) ----
#pragma unroll
  for (int reg = 0; reg < 4; ++reg) {
    float mx = -1e30f;
#pragma unroll
    for (int tn = 0; tn < 4; ++tn) {
      sacc[tn][reg] *= SCALING_;
      mx = fmaxf(mx, sacc[tn][reg]);
    }
#pragma unroll
    for (int o = 1; o <= 8; o <<= 1) mx = fmaxf(mx, __shfl_xor(mx, o, 64));
    float e_[4], sum = 0.f;
#pragma unroll
    for (int tn = 0; tn < 4; ++tn) {
      e_[tn] = __expf(sacc[tn][reg] - mx);
      sum += e_[tn];
    }
#pragma unroll
    for (int o = 1; o <= 8; o <<= 1) sum += __shfl_xor(sum, o, 64);
    const float pw = w / sum;
    const int srow = r0 + g * 4 + reg;
    unsigned p01 = cvt_pk_bf16(e_[0] * pw, e_[1] * pw);
    unsigned p23 = cvt_pk_bf16(e_[2] * pw, e_[3] * pw);
    lds_w16(Pl, srow, 2 * S_, (0 * 16 + rl) * 2, (short)p01);
    lds_w16(Pl, srow, 2 * S_, (1 * 16 + rl) * 2, (short)(p01 >> 16));
    lds_w16(Pl, srow, 2 * S_, (2 * 16 + rl) * 2, (short)p23);
    lds_w16(Pl, srow, 2 * S_, (3 * 16 + rl) * 2, (short)(p23 >> 16));
  }

  // ---- acc = phi @ St (global, baked swizzle), scale by cl ----
  f32x4 acc[8];
#pragma unroll
  for (int tn = 0; tn < 8; ++tn) acc[tn] = z4;

#pragma unroll
  for (int ks = 0; ks < 4; ++ks) {
    s16x8 a = swz_frag(phi, r0 + rl, 2 * F2_, (ks * 32 + kl) * 2);
#pragma unroll
    for (int tn = 0; tn < 8; ++tn) {
      s16x8 b = swz_frag(Sb, tn * 16 + rl, 2 * F2_, (ks * 32 + kl) * 2);
      acc[tn] = MFMA(a, b, acc[tn]);
    }
  }
#pragma unroll
  for (int tn = 0; tn < 8; ++tn)
#pragma unroll
    for (int reg = 0; reg < 4; ++reg) acc[tn][reg] *= cl[reg];

  // ---- acc += P @ V (global, baked swizzle) ----
#pragma unroll
  for (int ks = 0; ks < 2; ++ks) {
    s16x8 a = swz_frag(Pl, r0 + rl, 2 * S_, (ks * 32 + kl) * 2);
#pragma unroll
    for (int tn = 0; tn < 8; ++tn) {
      s16x8 b = swz_frag(VTb, tn * 16 + rl, 2 * S_, (ks * 32 + kl) * 2);
      acc[tn] = MFMA(a, b, acc[tn]);
    }
  }

  // ---- store ----
  float* Ob = Out + (size_t)blk * (S_ * D_);
#pragma unroll
  for (int tn = 0; tn < 8; ++tn)
#pragma unroll
    for (int reg = 0; reg < 4; ++reg) {
      int srow = r0 + g * 4 + reg;
      Ob[(size_t)srow * D_ + tn * 16 + rl] = acc[tn][reg];
    }
}

// ---------------------------------------------------------------------------
extern "C" void kernel_launch(void* const* d_in, const int* in_sizes, int n_in,
                              void* d_out, int out_size, void* d_ws, size_t ws_size,
                              hipStream_t stream)
{
  const float* Q = (const float*)d_in[0];
  const float* K = (const float*)d_in[1];
  const float* V = (const float*)d_in[2];
  const float* W = (const float*)d_in[3];
  const float* alpha = (const float*)d_in[4];
  float* Out = (float*)d_out;

  short* VT = (short*)d_ws;                              // 32 MiB
  short* St = VT + (size_t)NBT_ * D_ * S_;               // 64 MiB
  short* dZ = St + (size_t)NBT_ * F2_ * D_;              // 0.5 MiB
  short* Wt = dZ + (size_t)NBT_ * F2_;                   // 0.25 MiB

  hipLaunchKernelGGL(prep_w, dim3(H_), dim3(256), 0, stream, W, Wt);
  hipLaunchKernelGGL(bslh_phase1, dim3(NBT_), dim3(256), 0, stream,
                     K, V, Wt, VT, St, dZ);
  hipLaunchKernelGGL(bslh_scan, dim3(516), dim3(256), 0, stream, St, dZ);
  hipLaunchKernelGGL(bslh_phase3, dim3(NBT_), dim3(256), 0, stream,
                     Q, K, VT, Wt, St, dZ, alpha, Out);
}

// Round 11
// 180.358 us; speedup vs baseline: 1.0646x; 1.0646x over previous
//
#include <hip/hip_runtime.h>
#include <math.h>

// Problem constants (fixed by reference)
#define B_ 2
#define H_ 16
#define L_ 4096
#define D_ 128
#define F_ 64
#define F2_ 128
#define S_ 64
#define N_ 64
#define BH_ 32
#define NBT_ 2048
#define EPS_ 1e-6f
#define SCALING_ 0.08838834764831845f  // 128^-0.5

typedef float f32x4 __attribute__((ext_vector_type(4)));
typedef short s16x8 __attribute__((ext_vector_type(8)));
typedef short s16x4 __attribute__((ext_vector_type(4)));

#define MFMA(a, b, c) __builtin_amdgcn_mfma_f32_16x16x32_bf16(a, b, c, 0, 0, 0)

__device__ __forceinline__ short f2bf(float f) {
  unsigned u = __float_as_uint(f);
  u += 0x7fffu + ((u >> 16) & 1u);   // RNE
  return (short)(u >> 16);
}
__device__ __forceinline__ float bf2f(short s) {
  return __uint_as_float(((unsigned)(unsigned short)s) << 16);
}
__device__ __forceinline__ s16x8 pack8(f32x4 a, f32x4 b) {
  s16x8 r;
  r[0] = f2bf(a[0]); r[1] = f2bf(a[1]); r[2] = f2bf(a[2]); r[3] = f2bf(a[3]);
  r[4] = f2bf(b[0]); r[5] = f2bf(b[1]); r[6] = f2bf(b[2]); r[7] = f2bf(b[3]);
  return r;
}

// XOR swizzle: byte ^= (row&7)<<4 within a row; baked into St/VT global layouts.
__device__ __forceinline__ s16x8 swz_frag(const short* base, int row, int rowBytes, int colByte) {
  int byte = row * rowBytes + (colByte ^ ((row & 7) << 4));
  return *(const s16x8*)((const char*)base + byte);
}
__device__ __forceinline__ void lds_w16(short* lds, int row, int rowBytes, int colByte, short v) {
  int byte = row * rowBytes + (colByte ^ ((row & 7) << 4));
  *(short*)((char*)lds + byte) = v;
}

// ---------------------------------------------------------------------------
// prep_w: Wt[h][f][d] bf16 (transposed).
// ---------------------------------------------------------------------------
__global__ __launch_bounds__(256)
void prep_w(const float* __restrict__ W, short* __restrict__ Wt)
{
  const int h = blockIdx.x;
  const int tid = threadIdx.x;
  const int f = tid & 63, gq = tid >> 6;
  const float* Wh = W + (size_t)h * D_ * F_;
  short* Wo = Wt + (size_t)h * F_ * D_ + (size_t)f * D_ + gq * 32;
  short buf[32];
#pragma unroll
  for (int j = 0; j < 32; ++j) buf[j] = f2bf(Wh[(size_t)(gq * 32 + j) * F_ + f]);
#pragma unroll
  for (int j2 = 0; j2 < 4; ++j2) {
    s16x8 v;
#pragma unroll
    for (int e = 0; e < 8; ++e) v[e] = buf[j2 * 8 + e];
    *(s16x8*)(Wo + j2 * 8) = v;
  }
}

// ---- ping-pong load/step macros (named register groups, static indices) ----
#define W_LOAD(dst, ks) { _Pragma("unroll") \
  for (int tn = 0; tn < 4; ++tn) \
    dst[tn] = *(const s16x8*)(Wh + (size_t)(tn * 16 + rl) * D_ + (ks) * 32 + kl); }
#define U_STEP(cur, ks) { _Pragma("unroll") \
  for (int tn = 0; tn < 4; ++tn) uacc[tn] = MFMA(aq[ks], cur[tn], uacc[tn]); }
#define K_LOAD(dst, ks) { _Pragma("unroll") \
  for (int tn = 0; tn < 4; ++tn) { \
    const float* kp = Kb + (size_t)(tn * 16 + rl) * D_ + (ks) * 32 + kl; \
    dst[2 * tn] = *(const f32x4*)kp; dst[2 * tn + 1] = *(const f32x4*)(kp + 4); } }
#define K_STEP(cur, ks) { _Pragma("unroll") \
  for (int tn = 0; tn < 4; ++tn) { \
    s16x8 b = pack8(cur[2 * tn], cur[2 * tn + 1]); \
    sacc[tn] = MFMA(aq[ks], b, sacc[tn]); } }
#define S_LOAD(dst, ks) { _Pragma("unroll") \
  for (int tn = 0; tn < 8; ++tn) \
    dst[tn] = swz_frag(Sb, tn * 16 + rl, 2 * F2_, ((ks) * 32 + kl) * 2); }
#define S_STEP(cur, ks) { s16x8 a = swz_frag(phi, r0 + rl, 2 * F2_, ((ks) * 32 + kl) * 2); \
  _Pragma("unroll") for (int tn = 0; tn < 8; ++tn) acc[tn] = MFMA(a, cur[tn], acc[tn]); }
#define V_LOAD(dst, ks) { _Pragma("unroll") \
  for (int tn = 0; tn < 8; ++tn) \
    dst[tn] = swz_frag(VTb, tn * 16 + rl, 2 * S_, ((ks) * 32 + kl) * 2); }
#define V_STEP(cur, ks) { s16x8 a = swz_frag(Pl, r0 + rl, 2 * S_, ((ks) * 32 + kl) * 2); \
  _Pragma("unroll") for (int tn = 0; tn < 8; ++tn) acc[tn] = MFMA(a, cur[tn], acc[tn]); }

// ---------------------------------------------------------------------------
// phase1: batched V loads -> VTs image; ping-pong W/K loads for u = k@W;
// phi_k -> phiT; dZ; dSt (LDS MFMA); coalesced VT + St stores.
// ---------------------------------------------------------------------------
__global__ __launch_bounds__(256, 3)
void bslh_phase1(const float* __restrict__ K, const float* __restrict__ V,
                 const short* __restrict__ Wt, short* __restrict__ VT,
                 short* __restrict__ dSt, short* __restrict__ dZ)
{
  __shared__ __align__(16) char lds[32 * 1024];
  short* phiT = (short*)lds;              // 16KB [128 f][128B] swizzled
  short* VTs = (short*)(lds + 16384);     // 16KB [128 d][128B] baked layout

  const int blk = blockIdx.x;
  const int bh = blk / N_;
  const int h = bh % H_;
  const int tid = threadIdx.x;
  const int wave = tid >> 6, lane = tid & 63;
  const int rl = lane & 15, g = lane >> 4, kl = g * 8;
  const int r0 = wave * 16;

  const float* Kb = K + (size_t)blk * (S_ * D_);
  const short* Wh = Wt + (size_t)h * (F_ * D_);
  const f32x4 z4 = {0.f, 0.f, 0.f, 0.f};

  // ---- batch-issue: V (8), K row (8), W groups 0/1 ----
  f32x4 vv[8];
  {
    const f32x4* gv = (const f32x4*)(V + (size_t)blk * S_ * D_);
#pragma unroll
    for (int ii = 0; ii < 8; ++ii) vv[ii] = gv[tid + 256 * ii];
  }
  f32x4 kv[8];
  {
    const float* kp = Kb + (size_t)(r0 + rl) * D_ + kl;
#pragma unroll
    for (int i = 0; i < 8; ++i) kv[i] = *(const f32x4*)(kp + (i >> 1) * 32 + (i & 1) * 4);
  }
  s16x8 wA[4], wB[4];
  W_LOAD(wA, 0); W_LOAD(wB, 1);

  // ---- V transpose -> VTs (consumes vv; W/K still in flight) ----
#pragma unroll
  for (int ii = 0; ii < 8; ++ii) {
    int idx = tid + 256 * ii;
    int s = idx >> 5, c = (idx & 31) * 4;
    float m0 = vv[ii][0], m1 = vv[ii][1], m2 = vv[ii][2], m3 = vv[ii][3];
    float o0 = __shfl_xor(m0, 32, 64);
    float o1 = __shfl_xor(m1, 32, 64);
    float o2 = __shfl_xor(m2, 32, 64);
    float o3 = __shfl_xor(m3, 32, 64);
    if (!(tid & 32)) {
      float m[4] = {m0, m1, m2, m3};
      float o[4] = {o0, o1, o2, o3};
#pragma unroll
      for (int j = 0; j < 4; ++j) {
        int d = c + j;
        unsigned pk = (unsigned)(unsigned short)f2bf(m[j]) |
                      ((unsigned)(unsigned short)f2bf(o[j]) << 16);
        int byte = d * 128 + ((s * 2) ^ ((d & 7) << 4));
        *(unsigned*)((char*)VTs + byte) = pk;
      }
    }
  }

  // ---- u = k @ W (ping-pong W groups) ----
  s16x8 aq[4];
#pragma unroll
  for (int ks = 0; ks < 4; ++ks) aq[ks] = pack8(kv[2 * ks], kv[2 * ks + 1]);
  f32x4 uacc[4] = {z4, z4, z4, z4};
  U_STEP(wA, 0); W_LOAD(wA, 2);
  U_STEP(wB, 1); W_LOAD(wB, 3);
  U_STEP(wA, 2);
  U_STEP(wB, 3);

  // ---- phi = [softmax(u), softmax(-u)] -> phiT (transposed, swizzled) ----
#pragma unroll
  for (int reg = 0; reg < 4; ++reg) {
    float mx = -1e30f, mn = 1e30f;
#pragma unroll
    for (int tn = 0; tn < 4; ++tn) {
      mx = fmaxf(mx, uacc[tn][reg]);
      mn = fminf(mn, uacc[tn][reg]);
    }
#pragma unroll
    for (int o = 1; o <= 8; o <<= 1) {
      mx = fmaxf(mx, __shfl_xor(mx, o, 64));
      mn = fminf(mn, __shfl_xor(mn, o, 64));
    }
    float ep[4], em[4], sp = 0.f, sm = 0.f;
#pragma unroll
    for (int tn = 0; tn < 4; ++tn) {
      ep[tn] = __expf(uacc[tn][reg] - mx); sp += ep[tn];
      em[tn] = __expf(mn - uacc[tn][reg]); sm += em[tn];
    }
#pragma unroll
    for (int o = 1; o <= 8; o <<= 1) {
      sp += __shfl_xor(sp, o, 64);
      sm += __shfl_xor(sm, o, 64);
    }
    const float rp = 1.f / sp, rm = 1.f / sm;
    const int srow = r0 + g * 4 + reg;
#pragma unroll
    for (int tn = 0; tn < 4; ++tn) {
      int f = tn * 16 + rl;
      lds_w16(phiT, f,      2 * S_, srow * 2, f2bf(ep[tn] * rp));
      lds_w16(phiT, f + 64, 2 * S_, srow * 2, f2bf(em[tn] * rm));
    }
  }
  __syncthreads();   // phiT + VTs images complete

  // ---- write VT global (coalesced) ----
  {
    float4* dst = (float4*)(VT + (size_t)blk * (D_ * S_));
    const float4* src = (const float4*)VTs;
#pragma unroll
    for (int i = 0; i < 4; ++i) dst[tid + 256 * i] = src[tid + 256 * i];
  }

  // ---- dZ[f] = sum_s phi[s][f] (bf16) ----
  {
    const int f = tid >> 1, half = tid & 1;
    float z = 0.f;
#pragma unroll
    for (int j2 = 0; j2 < 4; ++j2) {
      s16x8 v = swz_frag(phiT, f, 2 * S_, (half * 32 + j2 * 8) * 2);
#pragma unroll
      for (int e = 0; e < 8; ++e) z += bf2f(v[e]);
    }
    z += __shfl_xor(z, 1, 64);
    if (half == 0) dZ[(size_t)blk * F2_ + f] = f2bf(z);
  }

  // ---- dSt[d][f]; wave owns d-rows 32w..32w+31 (LDS reads only) ----
  f32x4 acc[2][8];
#pragma unroll
  for (int tm = 0; tm < 2; ++tm)
#pragma unroll
    for (int tn = 0; tn < 8; ++tn) acc[tm][tn] = z4;

#pragma unroll
  for (int ks = 0; ks < 2; ++ks) {
    s16x8 a[2];
#pragma unroll
    for (int tm = 0; tm < 2; ++tm)
      a[tm] = swz_frag(VTs, wave * 32 + tm * 16 + rl, 2 * S_, (ks * 32 + kl) * 2);
#pragma unroll
    for (int tn = 0; tn < 8; ++tn) {
      s16x8 b = swz_frag(phiT, tn * 16 + rl, 2 * S_, (ks * 32 + kl) * 2);
#pragma unroll
      for (int tm = 0; tm < 2; ++tm)
        acc[tm][tn] = MFMA(a[tm], b, acc[tm][tn]);
    }
  }
  __syncthreads();   // reuse lds as St image

  // ---- pack acc into LDS St image (baked swizzle), coalesced store ----
  short* Stb = (short*)lds;
#pragma unroll
  for (int tm = 0; tm < 2; ++tm)
#pragma unroll
    for (int tn = 0; tn < 8; ++tn)
#pragma unroll
      for (int reg = 0; reg < 4; ++reg) {
        float v0 = acc[tm][tn][reg];
        float v1 = __shfl_xor(v0, 1, 64);
        if (!(lane & 1)) {
          int drow = wave * 32 + tm * 16 + g * 4 + reg;
          int fcol = tn * 16 + rl;
          unsigned pk = (unsigned)(unsigned short)f2bf(v0) |
                        ((unsigned)(unsigned short)f2bf(v1) << 16);
          int byte = drow * 256 + ((fcol * 2) ^ ((drow & 7) << 4));
          *(unsigned*)((char*)Stb + byte) = pk;
        }
      }
  __syncthreads();

  float4* dst = (float4*)(dSt + (size_t)blk * (F2_ * D_));
  const float4* srcl = (const float4*)lds;
#pragma unroll
  for (int i = 0; i < 8; ++i) dst[tid + 256 * i] = srcl[tid + 256 * i];
}

// ---------------------------------------------------------------------------
// scan: exclusive prefix over n. unroll 8 -> 8 independent loads in flight.
// ---------------------------------------------------------------------------
__global__ __launch_bounds__(256)
void bslh_scan(short* __restrict__ St, short* __restrict__ dZ)
{
  const int tid = threadIdx.x;
  if (blockIdx.x < 512) {
    const int idx = blockIdx.x * 256 + tid;      // 131072 threads
    const int bh = idx >> 12;
    const int rem = idx & 4095;
    short* p = St + (size_t)bh * N_ * (F2_ * D_) + (size_t)rem * 4;
    float run[4] = {0.f, 0.f, 0.f, 0.f};
#pragma unroll 8
    for (int n = 0; n < N_; ++n) {
      s16x4 v = *(const s16x4*)p;
      s16x4 o;
#pragma unroll
      for (int e = 0; e < 4; ++e) {
        o[e] = f2bf(run[e]);
        run[e] += bf2f(v[e]);
      }
      *(s16x4*)p = o;
      p += F2_ * D_;
    }
  } else {
    const int idx = (blockIdx.x - 512) * 256 + tid;  // 1024 threads
    const int bh = idx >> 5, e = idx & 31;
    short* p = dZ + (size_t)bh * N_ * F2_ + (size_t)e * 4;
    float run[4] = {0.f, 0.f, 0.f, 0.f};
#pragma unroll 8
    for (int n = 0; n < N_; ++n) {
      s16x4 v = *(const s16x4*)p;
      s16x4 o;
#pragma unroll
      for (int e2 = 0; e2 < 4; ++e2) {
        o[e2] = f2bf(run[e2]);
        run[e2] += bf2f(v[e2]);
      }
      *(s16x4*)p = o;
      p += F2_;
    }
  }
}

// ---------------------------------------------------------------------------
// phase3 — barrier-free + explicit ping-pong load groups: 8-16 VMEM loads
// in flight at all times; St group 0/1 issued before the softmax chains.
// ---------------------------------------------------------------------------
__global__ __launch_bounds__(256, 3)
void bslh_phase3(const float* __restrict__ Q, const float* __restrict__ K,
                 const short* __restrict__ VT, const short* __restrict__ Wt,
                 const short* __restrict__ St, const short* __restrict__ Zp,
                 const float* __restrict__ alphap, float* __restrict__ Out)
{
  __shared__ __align__(16) short phi[S_ * F2_];  // 16KB; rows r0..r0+15 per wave
  __shared__ __align__(16) short Pl[S_ * S_];    // 8KB;  rows r0..r0+15 per wave

  const int blk = blockIdx.x;
  const int bh = blk / N_;
  const int h = bh % H_;
  const int tid = threadIdx.x;
  const int wave = tid >> 6, lane = tid & 63;
  const int rl = lane & 15, g = lane >> 4, kl = g * 8;
  const int r0 = wave * 16;

  const float* Qb = Q + (size_t)blk * (S_ * D_);
  const float* Kb = K + (size_t)blk * (S_ * D_);
  const short* Sb = St + (size_t)blk * (F2_ * D_);
  const short* VTb = VT + (size_t)blk * (D_ * S_);
  const short* Wh = Wt + (size_t)h * (F_ * D_);
  const short* Zb = Zp + (size_t)blk * F2_;
  const float w = 1.f / (1.f + __expf(-alphap[0]));
  const f32x4 z4 = {0.f, 0.f, 0.f, 0.f};

  // ---- batch-issue: Q row (8 f32x4), W groups 0/1, K group 0 ----
  f32x4 qv[8];
  {
    const float* qp = Qb + (size_t)(r0 + rl) * D_ + kl;
#pragma unroll
    for (int i = 0; i < 8; ++i) qv[i] = *(const f32x4*)(qp + (i >> 1) * 32 + (i & 1) * 4);
  }
  s16x8 wA[4], wB[4];
  W_LOAD(wA, 0); W_LOAD(wB, 1);
  f32x4 kA[8], kB[8];
  K_LOAD(kA, 0);

  float zf0[4], zf1[4];
#pragma unroll
  for (int tn = 0; tn < 4; ++tn) {
    zf0[tn] = bf2f(Zb[tn * 16 + rl]);
    zf1[tn] = bf2f(Zb[64 + tn * 16 + rl]);
  }

  // ---- u = q@W and scores = q@k^T, interleaved ping-pong ----
  s16x8 aq[4];
#pragma unroll
  for (int ks = 0; ks < 4; ++ks) aq[ks] = pack8(qv[2 * ks], qv[2 * ks + 1]);
  f32x4 uacc[4] = {z4, z4, z4, z4};
  f32x4 sacc[4] = {z4, z4, z4, z4};
  U_STEP(wA, 0); W_LOAD(wA, 2);
  K_LOAD(kB, 1);
  U_STEP(wB, 1); W_LOAD(wB, 3);
  K_STEP(kA, 0); K_LOAD(kA, 2);
  U_STEP(wA, 2);
  K_STEP(kB, 1); K_LOAD(kB, 3);
  U_STEP(wB, 3);
  K_STEP(kA, 2);
  K_STEP(kB, 3);

  // ---- issue St groups 0/1 now; latency hides under both softmax chains ----
  s16x8 sA[8], sB[8];
  S_LOAD(sA, 0); S_LOAD(sB, 1);

  // ---- phi_q softmaxes + in-register cl ----
  float cl[4];
#pragma unroll
  for (int reg = 0; reg < 4; ++reg) {
    float mx = -1e30f, mn = 1e30f;
#pragma unroll
    for (int tn = 0; tn < 4; ++tn) {
      mx = fmaxf(mx, uacc[tn][reg]);
      mn = fminf(mn, uacc[tn][reg]);
    }
#pragma unroll
    for (int o = 1; o <= 8; o <<= 1) {
      mx = fmaxf(mx, __shfl_xor(mx, o, 64));
      mn = fminf(mn, __shfl_xor(mn, o, 64));
    }
    float ep[4], em[4], sp = 0.f, sm = 0.f;
#pragma unroll
    for (int tn = 0; tn < 4; ++tn) {
      ep[tn] = __expf(uacc[tn][reg] - mx); sp += ep[tn];
      em[tn] = __expf(mn - uacc[tn][reg]); sm += em[tn];
    }
#pragma unroll
    for (int o = 1; o <= 8; o <<= 1) {
      sp += __shfl_xor(sp, o, 64);
      sm += __shfl_xor(sm, o, 64);
    }
    const float rp = 1.f / sp, rm = 1.f / sm;
    const int srow = r0 + g * 4 + reg;
    float dp = 0.f;
#pragma unroll
    for (int tn = 0; tn < 4; ++tn) {
      float pv = ep[tn] * rp, mv = em[tn] * rm;
      dp = fmaf(pv, zf0[tn], dp);
      dp = fmaf(mv, zf1[tn], dp);
      int f = tn * 16 + rl;
      lds_w16(phi, srow, 2 * F2_, f * 2,        f2bf(pv));
      lds_w16(phi, srow, 2 * F2_, (f + 64) * 2, f2bf(mv));
    }
#pragma unroll
    for (int o = 1; o <= 8; o <<= 1) dp += __shfl_xor(dp, o, 64);
    cl[reg] = (1.f - w) / fmaxf(dp, EPS_);
  }

  // ---- scores softmax -> Pl (wave-private) ----
#pragma unroll
  for (int reg = 0; reg < 4; ++reg) {
    float mx = -1e30f;
#pragma unroll
    for (int tn = 0; tn < 4; ++tn) {
      sacc[tn][reg] *= SCALING_;
      mx = fmaxf(mx, sacc[tn][reg]);
    }
#pragma unroll
    for (int o = 1; o <= 8; o <<= 1) mx = fmaxf(mx, __shfl_xor(mx, o, 64));
    float e_[4], sum = 0.f;
#pragma unroll
    for (int tn = 0; tn < 4; ++tn) {
      e_[tn] = __expf(sacc[tn][reg] - mx);
      sum += e_[tn];
    }
#pragma unroll
    for (int o = 1; o <= 8; o <<= 1) sum += __shfl_xor(sum, o, 64);
    const float pw = w / sum;
    const int srow = r0 + g * 4 + reg;
#pragma unroll
    for (int tn = 0; tn < 4; ++tn)
      lds_w16(Pl, srow, 2 * S_, (tn * 16 + rl) * 2, f2bf(e_[tn] * pw));
  }

  // ---- acc = phi @ St (ping-pong; groups 0/1 already in flight) ----
  f32x4 acc[8];
#pragma unroll
  for (int tn = 0; tn < 8; ++tn) acc[tn] = z4;

  S_STEP(sA, 0); S_LOAD(sA, 2);
  S_STEP(sB, 1); S_LOAD(sB, 3);
  S_STEP(sA, 2);
  s16x8 vA[8];
  V_LOAD(vA, 0);
  S_STEP(sB, 3);
  s16x8 vB[8];
  V_LOAD(vB, 1);

#pragma unroll
  for (int tn = 0; tn < 8; ++tn)
#pragma unroll
    for (int reg = 0; reg < 4; ++reg) acc[tn][reg] *= cl[reg];

  // ---- acc += P @ V ----
  V_STEP(vA, 0);
  V_STEP(vB, 1);

  // ---- store ----
  float* Ob = Out + (size_t)blk * (S_ * D_);
#pragma unroll
  for (int tn = 0; tn < 8; ++tn)
#pragma unroll
    for (int reg = 0; reg < 4; ++reg) {
      int srow = r0 + g * 4 + reg;
      Ob[(size_t)srow * D_ + tn * 16 + rl] = acc[tn][reg];
    }
}

// ---------------------------------------------------------------------------
extern "C" void kernel_launch(void* const* d_in, const int* in_sizes, int n_in,
                              void* d_out, int out_size, void* d_ws, size_t ws_size,
                              hipStream_t stream)
{
  const float* Q = (const float*)d_in[0];
  const float* K = (const float*)d_in[1];
  const float* V = (const float*)d_in[2];
  const float* W = (const float*)d_in[3];
  const float* alpha = (const float*)d_in[4];
  float* Out = (float*)d_out;

  short* VT = (short*)d_ws;                              // 32 MiB
  short* St = VT + (size_t)NBT_ * D_ * S_;               // 64 MiB
  short* dZ = St + (size_t)NBT_ * F2_ * D_;              // 0.5 MiB
  short* Wt = dZ + (size_t)NBT_ * F2_;                   // 0.25 MiB

  hipLaunchKernelGGL(prep_w, dim3(H_), dim3(256), 0, stream, W, Wt);
  hipLaunchKernelGGL(bslh_phase1, dim3(NBT_), dim3(256), 0, stream,
                     K, V, Wt, VT, St, dZ);
  hipLaunchKernelGGL(bslh_scan, dim3(516), dim3(256), 0, stream, St, dZ);
  hipLaunchKernelGGL(bslh_phase3, dim3(NBT_), dim3(256), 0, stream,
                     Q, K, VT, Wt, St, dZ, alpha, Out);
}